// Round 3
// baseline (656.624 us; speedup 1.0000x reference)
//
#include <hip/hip_runtime.h>
#include <hip/hip_bf16.h>

typedef __hip_bfloat16 bf16;
typedef __attribute__((ext_vector_type(8))) short short8;   // 8 bf16 (4 VGPRs)
typedef __attribute__((ext_vector_type(4))) float f32x4;    // MFMA C/D

// async global->LDS, 16B per lane; LDS dest = wave-uniform base + lane*16
__device__ __forceinline__ void gload_lds16(const void* g, void* l) {
    __builtin_amdgcn_global_load_lds(
        (const __attribute__((address_space(1))) void*)g,
        (__attribute__((address_space(3))) void*)l, 16, 0, 0);
}

__device__ __forceinline__ void store_out(bf16* p, float v)  { *p = __float2bfloat16(v); }
__device__ __forceinline__ void store_out(float* p, float v) { *p = v; }

// ---------------------------------------------------------------------------
// fp32 -> bf16 conversion, 8 elems/thread. n must be a multiple of 2048.
// ---------------------------------------------------------------------------
__global__ __launch_bounds__(256)
void cvt_f32_bf16(const float* __restrict__ in, bf16* __restrict__ out, long n)
{
    const long i = ((long)blockIdx.x * 256 + threadIdx.x) * 8;
    if (i + 8 > n) return;
    float4 a = *(const float4*)(in + i);
    float4 b = *(const float4*)(in + i + 4);
    bf16 o[8];
    o[0] = __float2bfloat16(a.x); o[1] = __float2bfloat16(a.y);
    o[2] = __float2bfloat16(a.z); o[3] = __float2bfloat16(a.w);
    o[4] = __float2bfloat16(b.x); o[5] = __float2bfloat16(b.y);
    o[6] = __float2bfloat16(b.z); o[7] = __float2bfloat16(b.w);
    *(uint4*)(out + i) = *(const uint4*)o;
}

// ---------------------------------------------------------------------------
// C(M,N) = A(M,K) * Bt(N,K)^T + bias(N); A,Bt bf16, bias fp32, fp32 accum.
// 128x128 tile, BK=32, 256 threads = 4 waves in 2x2, each wave 64x64 (4x4 MFMA)
// OutT = bf16 or float.
// ---------------------------------------------------------------------------
template <typename OutT>
__global__ __launch_bounds__(256)
void gemm_bt_bias(const bf16* __restrict__ A, const bf16* __restrict__ Bt,
                  const float* __restrict__ bias, OutT* __restrict__ C,
                  int N, int K)
{
    __shared__ bf16 As[128 * 32];   // row-major [128][32]
    __shared__ bf16 Bs[128 * 32];

    const int tid = threadIdx.x;
    const int wv  = tid >> 6;           // wave 0..3
    const int ln  = tid & 63;
    const int l15 = ln & 15;
    const int qd  = ln >> 4;            // quad 0..3
    const int wm  = wv >> 1, wn = wv & 1;
    const long m0 = (long)blockIdx.y * 128;
    const long n0 = (long)blockIdx.x * 128;

    // staging geometry: thread tid loads elems e..e+7 of the 4096-elem tile
    const int e0 = tid * 8;
    const int e1 = (256 + tid) * 8;
    const int ar0 = e0 >> 5, ac0 = e0 & 31;
    const int ar1 = e1 >> 5, ac1 = e1 & 31;
    bf16* lA0 = &As[wv * 512];          // wave-uniform LDS bases (512 elems = 1KB)
    bf16* lA1 = &As[2048 + wv * 512];
    bf16* lB0 = &Bs[wv * 512];
    bf16* lB1 = &Bs[2048 + wv * 512];

    f32x4 acc[4][4] = {};

    for (int k0 = 0; k0 < K; k0 += 32) {
        gload_lds16(A  + (m0 + ar0) * K + k0 + ac0, lA0);
        gload_lds16(A  + (m0 + ar1) * K + k0 + ac1, lA1);
        gload_lds16(Bt + (n0 + ar0) * K + k0 + ac0, lB0);
        gload_lds16(Bt + (n0 + ar1) * K + k0 + ac1, lB1);
        __syncthreads();   // drains vmcnt before any wave reads LDS

        short8 af[4], bfr[4];
#pragma unroll
        for (int mi = 0; mi < 4; ++mi)
            af[mi] = *(const short8*)&As[(wm * 64 + mi * 16 + l15) * 32 + qd * 8];
#pragma unroll
        for (int ni = 0; ni < 4; ++ni)
            bfr[ni] = *(const short8*)&Bs[(wn * 64 + ni * 16 + l15) * 32 + qd * 8];
#pragma unroll
        for (int mi = 0; mi < 4; ++mi)
#pragma unroll
            for (int ni = 0; ni < 4; ++ni)
                acc[mi][ni] = __builtin_amdgcn_mfma_f32_16x16x32_bf16(
                    af[mi], bfr[ni], acc[mi][ni], 0, 0, 0);
        __syncthreads();   // all reads done before next-iter staging overwrites
    }

    // epilogue: C/D layout col=lane&15, row=quad*4+reg
    const long ccol = n0 + wn * 64;
    float bsv[4];
#pragma unroll
    for (int ni = 0; ni < 4; ++ni)
        bsv[ni] = bias[ccol + ni * 16 + l15];
#pragma unroll
    for (int mi = 0; mi < 4; ++mi) {
#pragma unroll
        for (int r = 0; r < 4; ++r) {
            const long row = m0 + wm * 64 + mi * 16 + qd * 4 + r;
            OutT* cp = C + row * N + ccol + l15;
#pragma unroll
            for (int ni = 0; ni < 4; ++ni)
                store_out(cp + ni * 16, acc[mi][ni][r] + bsv[ni]);
        }
    }
}

// ---------------------------------------------------------------------------
// Blocked local attention on a CHUNK of tokens (bf16 in/out).
// qkv: (CH, 3072); out: (CH, 1024). blockIdx.x = 64-token block, .y = head.
// S = (Q*0.125) K^T -> softmax -> O = P V via 16x16x32 bf16 MFMA.
// ---------------------------------------------------------------------------
#define LROW 72   // padded LDS row (16B-aligned stride, breaks 128B bank period)

__global__ __launch_bounds__(256)
void attn_local(const bf16* __restrict__ qkv, bf16* __restrict__ out)
{
    __shared__ bf16 Qs[64 * LROW];
    __shared__ bf16 Ks[64 * LROW];
    __shared__ bf16 Vt[64 * LROW];   // transposed: Vt[d][m]
    __shared__ bf16 Ps[64 * LROW];

    const int cb = blockIdx.x;               // token block within chunk
    const int h  = blockIdx.y;               // head
    const int tid = threadIdx.x;

    const long qoff = (long)cb * 64 * 3072 + h * 64;   // q; +1024 = k, +2048 = v

    // load Q, K row-major; V transposed. 4096 elems each, 16 per thread.
#pragma unroll
    for (int p = 0; p < 2; ++p) {
        const int e = (p * 256 + tid) * 8;
        const int tk = e >> 6, cl = e & 63;
        const long g = qoff + (long)tk * 3072 + cl;
        *(uint4*)&Qs[tk * LROW + cl] = *(const uint4*)&qkv[g];
        *(uint4*)&Ks[tk * LROW + cl] = *(const uint4*)&qkv[g + 1024];
        uint4 vv = *(const uint4*)&qkv[g + 2048];
        const bf16* vp = (const bf16*)&vv;
#pragma unroll
        for (int j = 0; j < 8; ++j)
            Vt[(cl + j) * LROW + tk] = vp[j];
    }
    __syncthreads();

    const int wv = tid >> 6, ln = tid & 63, l15 = ln & 15, qd = ln >> 4;

    // S slab: wave wv handles query rows wv*16 .. wv*16+15
    f32x4 sacc[4] = {};
#pragma unroll
    for (int kk = 0; kk < 64; kk += 32) {
        short8 aq = *(const short8*)&Qs[(wv * 16 + l15) * LROW + kk + qd * 8];
#pragma unroll
        for (int ni = 0; ni < 4; ++ni) {
            short8 bk = *(const short8*)&Ks[(ni * 16 + l15) * LROW + kk + qd * 8];
            sacc[ni] = __builtin_amdgcn_mfma_f32_16x16x32_bf16(aq, bk, sacc[ni], 0, 0, 0);
        }
    }

    // softmax over 64 cols; row = wv*16 + qd*4 + r; cols = ni*16 + l15.
    // scale folded here: softmax(0.125 * S).
    float linv[4];
#pragma unroll
    for (int r = 0; r < 4; ++r) {
        float m = -3.4e38f;
#pragma unroll
        for (int ni = 0; ni < 4; ++ni) m = fmaxf(m, sacc[ni][r]);
#pragma unroll
        for (int off = 1; off < 16; off <<= 1) m = fmaxf(m, __shfl_xor(m, off));
        float s = 0.f, pv[4];
#pragma unroll
        for (int ni = 0; ni < 4; ++ni) {
            pv[ni] = __expf(0.125f * (sacc[ni][r] - m));
            s += pv[ni];
        }
#pragma unroll
        for (int off = 1; off < 16; off <<= 1) s += __shfl_xor(s, off);
        linv[r] = 1.f / s;
        const int row = wv * 16 + qd * 4 + r;
#pragma unroll
        for (int ni = 0; ni < 4; ++ni)
            Ps[row * LROW + ni * 16 + l15] = __float2bfloat16(pv[ni]);
    }
    __syncthreads();

    // O = P V: A-frag from Ps (A[m=l15][k]), B-frag from Vt (B[n=d][k=m])
    f32x4 oacc[4] = {};
#pragma unroll
    for (int kk = 0; kk < 64; kk += 32) {
        short8 ap = *(const short8*)&Ps[(wv * 16 + l15) * LROW + kk + qd * 8];
#pragma unroll
        for (int ni = 0; ni < 4; ++ni) {
            short8 bv = *(const short8*)&Vt[(ni * 16 + l15) * LROW + kk + qd * 8];
            oacc[ni] = __builtin_amdgcn_mfma_f32_16x16x32_bf16(ap, bv, oacc[ni], 0, 0, 0);
        }
    }

    const long obase = (long)cb * 64 * 1024 + h * 64;
#pragma unroll
    for (int r = 0; r < 4; ++r) {
        const int row = wv * 16 + qd * 4 + r;
#pragma unroll
        for (int ni = 0; ni < 4; ++ni)
            out[obase + (long)row * 1024 + ni * 16 + l15] =
                __float2bfloat16(oacc[ni][r] * linv[r]);
    }
}

// ---------------------------------------------------------------------------
extern "C" void kernel_launch(void* const* d_in, const int* in_sizes, int n_in,
                              void* d_out, int out_size, void* d_ws, size_t ws_size,
                              hipStream_t stream) {
    const float* x     = (const float*)d_in[0];   // (8, 4096, 1024) fp32
    const float* W_qkv = (const float*)d_in[1];   // (3072, 1024)    fp32
    const float* b_qkv = (const float*)d_in[2];   // (3072,)         fp32
    const float* W_out = (const float*)d_in[3];   // (1024, 1024)    fp32
    const float* b_out = (const float*)d_in[4];   // (1024,)         fp32
    float* out = (float*)d_out;                   // 32768 x 1024    fp32

    // Fixed bf16 slabs for weights: W_qkv 3072x1024, W_out 1024x1024.
    bf16* Wqkv_b = (bf16*)d_ws;                           // 6.29 MB
    bf16* Wout_b = Wqkv_b + (size_t)3072 * 1024;          // 2.10 MB
    bf16* chunk0 = Wout_b + (size_t)1024 * 1024;
    const size_t fixed_bytes = ((size_t)3072 * 1024 + (size_t)1024 * 1024) * 2;

    // Per-chunk slabs: xb CHx1024, qkvb CHx3072, attnb CHx1024 (bf16)
    // -> CH * 10240 bytes.
    static const int cands[9] = {32768, 16384, 8192, 4096, 2048, 1024, 512, 256, 128};
    int CH = 128;
    for (int i = 0; i < 9; ++i)
        if (fixed_bytes + (size_t)cands[i] * 10240 <= ws_size) { CH = cands[i]; break; }

    bf16* xb    = chunk0;                        // CH x 1024
    bf16* qkvb  = xb + (size_t)CH * 1024;        // CH x 3072
    bf16* attnb = qkvb + (size_t)CH * 3072;      // CH x 1024

    const dim3 blk(256);

    // one-time weight conversion (cheap; done every call for graph safety)
    cvt_f32_bf16<<<dim3((3072 * 1024) / 2048), blk, 0, stream>>>(W_qkv, Wqkv_b, 3072 * 1024);
    cvt_f32_bf16<<<dim3((1024 * 1024) / 2048), blk, 0, stream>>>(W_out, Wout_b, 1024 * 1024);

    for (int c0 = 0; c0 < 32768; c0 += CH) {
        const long ne = (long)CH * 1024;
        cvt_f32_bf16<<<dim3((int)(ne / 2048)), blk, 0, stream>>>(x + (size_t)c0 * 1024, xb, ne);
        // qkv = xb @ Wqkv^T + b_qkv   (M=CH, N=3072, K=1024), bf16 out
        gemm_bt_bias<bf16><<<dim3(3072 / 128, CH / 128), blk, 0, stream>>>(
            xb, Wqkv_b, b_qkv, qkvb, 3072, 1024);
        // blocked local attention on the chunk
        attn_local<<<dim3(CH / 64, 16), blk, 0, stream>>>(qkvb, attnb);
        // out = attnb @ Wout^T + b_out (M=CH, N=1024, K=1024), fp32 out
        gemm_bt_bias<float><<<dim3(1024 / 128, CH / 128), blk, 0, stream>>>(
            attnb, Wout_b, b_out, out + (size_t)c0 * 1024, 1024, 1024);
    }
}